// Round 3
// baseline (728.792 us; speedup 1.0000x reference)
//
#include <hip/hip_runtime.h>
#include <math.h>

#define NN 50000
#define EE 800000
#define FIN 100
#define HH 64
#define CC 18

// ---------------- p = x @ fW1  (no bias; bias folded after aggregation) ----
__global__ __launch_bounds__(256) void k_gemm_first(
    const float* __restrict__ x, const float* __restrict__ W,
    float* __restrict__ p) {
  __shared__ float Ws[FIN * HH];   // 25.6 KB
  __shared__ float xs[64 * FIN];   // 25.6 KB
  int t = threadIdx.x;
  for (int i = t; i < FIN * HH; i += 256) Ws[i] = W[i];
  int n0 = blockIdx.x * 64;
  for (int i = t; i < 64 * FIN; i += 256) {
    int r = i / FIN, c = i - r * FIN;
    int n = n0 + r;
    xs[i] = (n < NN) ? x[n * FIN + c] : 0.f;
  }
  __syncthreads();
  int j = t & 63, nl = t >> 6;
  float acc[16];
#pragma unroll
  for (int q = 0; q < 16; ++q) acc[q] = 0.f;
  for (int k = 0; k < FIN; ++k) {
    float w = Ws[k * HH + j];
#pragma unroll
    for (int q = 0; q < 16; ++q)
      acc[q] = fmaf(xs[(nl + q * 4) * FIN + k], w, acc[q]);
  }
#pragma unroll
  for (int q = 0; q < 16; ++q) {
    int n = n0 + nl + q * 4;
    if (n < NN) p[n * HH + j] = acc[q];
  }
}

// ---------------- CSR build ------------------------------------------------
__global__ __launch_bounds__(256) void k_count(const int* __restrict__ ei,
                                               int* __restrict__ counts) {
  for (int e = blockIdx.x * 256 + threadIdx.x; e < EE; e += gridDim.x * 256)
    atomicAdd(&counts[ei[EE + e]], 1);
}

// single block, 1024 threads, 2-pass chunk scan: counts -> rowptr, cursor
__global__ __launch_bounds__(1024) void k_scan(const int* __restrict__ counts,
                                               int* __restrict__ rowptr,
                                               int* __restrict__ cursor) {
  __shared__ int wtot[16];
  int t = threadIdx.x;
  int lane = t & 63, wid = t >> 6;
  const int per = (NN + 1023) / 1024;  // 49
  int b0 = t * per;
  int e0 = min(b0 + per, NN);
  int s = 0;
  for (int i = b0; i < e0; ++i) s += counts[i];
  // block-wide exclusive scan of per-thread sums
  int x = s;
#pragma unroll
  for (int off = 1; off < 64; off <<= 1) {
    int y = __shfl_up(x, off);
    if (lane >= off) x += y;
  }
  if (lane == 63) wtot[wid] = x;
  __syncthreads();
  int woff = 0;
  for (int w = 0; w < wid; ++w) woff += wtot[w];
  int run = woff + x - s;  // exclusive prefix of this thread's chunk
  for (int i = b0; i < e0; ++i) {
    rowptr[i] = run;
    cursor[i] = run;
    run += counts[i];
  }
  if (t == 1023) rowptr[NN] = run;
}

__global__ __launch_bounds__(256) void k_fill(const int* __restrict__ ei,
                                              int* __restrict__ cursor,
                                              int* __restrict__ eidx) {
  for (int e = blockIdx.x * 256 + threadIdx.x; e < EE; e += gridDim.x * 256) {
    int s = ei[e], d = ei[EE + e];
    int pos = atomicAdd(&cursor[d], 1);
    eidx[pos] = s;
  }
}

// ---------------- gather: agg[n][j] = sum feat[src][j] over in-edges -------
__global__ __launch_bounds__(256) void k_gather(
    const float* __restrict__ feat, const int* __restrict__ rowptr,
    const int* __restrict__ eidx, float* __restrict__ agg) {
  int j = threadIdx.x & 63, wv = threadIdx.x >> 6;
  int wave = blockIdx.x * 4 + wv;
  int nw = gridDim.x * 4;
  for (int n = wave; n < NN; n += nw) {
    int beg = rowptr[n], end = rowptr[n + 1];
    float a = 0.f;
    for (int i0 = beg; i0 < end; i0 += 64) {
      int cnt = min(end - i0, 64);
      int eid = (j < cnt) ? eidx[i0 + j] : 0;
      int k = 0;
      for (; k + 8 <= cnt; k += 8) {
        int s[8];
        float v[8];
#pragma unroll
        for (int q = 0; q < 8; ++q) s[q] = __shfl(eid, k + q);
#pragma unroll
        for (int q = 0; q < 8; ++q) v[q] = feat[s[q] * HH + j];
        a += ((v[0] + v[1]) + (v[2] + v[3])) + ((v[4] + v[5]) + (v[6] + v[7]));
      }
      for (; k < cnt; ++k) a += feat[__shfl(eid, k) * HH + j];
    }
    agg[n * HH + j] = a;
  }
}

// -------- first conv MLP: z=(1+e)p+agg+b1; relu; @W2+b2; relu; BN ----------
__global__ __launch_bounds__(256) void k_mlp_first(
    const float* __restrict__ p, const float* __restrict__ agg,
    const float* __restrict__ epsv, const float* __restrict__ b1,
    const float* __restrict__ W2, const float* __restrict__ b2,
    const float* __restrict__ g, const float* __restrict__ be,
    const float* __restrict__ mu, const float* __restrict__ var,
    float* __restrict__ out) {
  __shared__ float W2s[HH * HH];  // 16 KB
  int t = threadIdx.x;
  for (int i = t; i < HH * HH; i += 256) W2s[i] = W2[i];
  __syncthreads();
  int j = t & 63, wv = t >> 6;
  float e0 = 1.f + epsv[0];
  float b1j = b1[j], b2j = b2[j];
  float sj = g[j] * rsqrtf(var[j] + 1e-5f);
  float bj = be[j] - mu[j] * sj;
  int wave = blockIdx.x * 4 + wv;
  int nw = gridDim.x * 4;
  for (int n = wave; n < NN; n += nw) {
    float a = fmaf(e0, p[n * HH + j], agg[n * HH + j]) + b1j;
    float tv = fmaxf(a, 0.f);
    float u = b2j;
#pragma unroll
    for (int k = 0; k < HH; ++k)
      u = fmaf(__shfl(tv, k), W2s[k * HH + j], u);
    float h = fmaxf(u, 0.f);
    out[n * HH + j] = fmaf(h, sj, bj);
  }
}

// -------- GIN layer MLP: z=(1+e)h+agg; relu(z@W1+b1)@W2+b2; relu; BN -------
__global__ __launch_bounds__(256) void k_mlp_layer(
    const float* __restrict__ h, const float* __restrict__ agg,
    const float* __restrict__ epsv, const float* __restrict__ W1,
    const float* __restrict__ b1, const float* __restrict__ W2,
    const float* __restrict__ b2, const float* __restrict__ g,
    const float* __restrict__ be, const float* __restrict__ mu,
    const float* __restrict__ var, float* __restrict__ out) {
  __shared__ float W1s[HH * HH];
  __shared__ float W2s[HH * HH];  // 32 KB total
  int t = threadIdx.x;
  for (int i = t; i < HH * HH; i += 256) {
    W1s[i] = W1[i];
    W2s[i] = W2[i];
  }
  __syncthreads();
  int j = t & 63, wv = t >> 6;
  float e0 = 1.f + epsv[0];
  float b1j = b1[j], b2j = b2[j];
  float sj = g[j] * rsqrtf(var[j] + 1e-5f);
  float bj = be[j] - mu[j] * sj;
  int wave = blockIdx.x * 4 + wv;
  int nw = gridDim.x * 4;
  for (int n = wave; n < NN; n += nw) {
    float z = fmaf(e0, h[n * HH + j], agg[n * HH + j]);
    float tv = b1j;
#pragma unroll
    for (int k = 0; k < HH; ++k)
      tv = fmaf(__shfl(z, k), W1s[k * HH + j], tv);
    tv = fmaxf(tv, 0.f);
    float u = b2j;
#pragma unroll
    for (int k = 0; k < HH; ++k)
      u = fmaf(__shfl(tv, k), W2s[k * HH + j], u);
    float hv = fmaxf(u, 0.f);
    out[n * HH + j] = fmaf(hv, sj, bj);
  }
}

// -------- readout: relu(h@L1+b)@L2+b2 -> log_softmax -----------------------
__global__ __launch_bounds__(256) void k_readout(
    const float* __restrict__ h, const float* __restrict__ W1,
    const float* __restrict__ b1, const float* __restrict__ W2,
    const float* __restrict__ b2, float* __restrict__ out) {
  __shared__ float W1s[HH * HH];
  __shared__ float W2s[HH * CC + 64];
  int t = threadIdx.x;
  for (int i = t; i < HH * HH; i += 256) W1s[i] = W1[i];
  for (int i = t; i < HH * CC + 64; i += 256)
    W2s[i] = (i < HH * CC) ? W2[i] : 0.f;
  __syncthreads();
  int j = t & 63, wv = t >> 6;
  float b1j = b1[j];
  float b2j = (j < CC) ? b2[j] : 0.f;
  int wave = blockIdx.x * 4 + wv;
  int nw = gridDim.x * 4;
  for (int n = wave; n < NN; n += nw) {
    float hv = h[n * HH + j];
    float r = b1j;
#pragma unroll
    for (int k = 0; k < HH; ++k)
      r = fmaf(__shfl(hv, k), W1s[k * HH + j], r);
    r = fmaxf(r, 0.f);
    float o = b2j;
#pragma unroll
    for (int k = 0; k < HH; ++k) {
      float rk = __shfl(r, k);
      o = fmaf(rk, W2s[k * CC + j], o);  // lanes >=18 compute garbage, masked
    }
    float om = (j < CC) ? o : -3.4e38f;
    float mx = om;
#pragma unroll
    for (int m = 32; m >= 1; m >>= 1) mx = fmaxf(mx, __shfl_xor(mx, m));
    float ex = (j < CC) ? expf(o - mx) : 0.f;
    float sm = ex;
#pragma unroll
    for (int m = 32; m >= 1; m >>= 1) sm += __shfl_xor(sm, m);
    if (j < CC) out[n * CC + j] = o - mx - logf(sm);
  }
}

extern "C" void kernel_launch(void* const* d_in, const int* in_sizes, int n_in,
                              void* d_out, int out_size, void* d_ws,
                              size_t ws_size, hipStream_t stream) {
  const float* x = (const float*)d_in[0];
  const int* ei = (const int*)d_in[1];
  const float* eps = (const float*)d_in[2];
  const float* fW1 = (const float*)d_in[3];
  const float* fb1 = (const float*)d_in[4];
  const float* fW2 = (const float*)d_in[5];
  const float* fb2 = (const float*)d_in[6];
  const float* W1s = (const float*)d_in[7];
  const float* b1s = (const float*)d_in[8];
  const float* W2s = (const float*)d_in[9];
  const float* b2s = (const float*)d_in[10];
  const float* bn_g = (const float*)d_in[11];
  const float* bn_b = (const float*)d_in[12];
  const float* bn_m = (const float*)d_in[13];
  const float* bn_v = (const float*)d_in[14];
  const float* l1W = (const float*)d_in[15];
  const float* l1b = (const float*)d_in[16];
  const float* l2W = (const float*)d_in[17];
  const float* l2b = (const float*)d_in[18];
  float* out = (float*)d_out;

  // ws layout: eidx[EE] | rowptr[NN+1] | pad | buf0 | buf1(agg) | buf2
  // counts/cursor overlay buf0 (dead before k_gemm_first writes buf0).
  int* eidx = (int*)d_ws;
  int* rowptr = eidx + EE;
  size_t int_elems = (size_t)EE + NN + 1;
  size_t f_off = (int_elems + 3) & ~(size_t)3;  // 16B align
  const size_t NH = (size_t)NN * HH;
  float* buf0 = (float*)d_ws + f_off;  // p / h
  float* buf1 = buf0 + NH;             // agg
  float* buf2 = buf1 + NH;             // h alt
  int* counts = (int*)buf0;            // overlay, dead after k_scan
  int* cursor = counts + NN;           // overlay, dead after k_fill

  // CSR build
  hipMemsetAsync(counts, 0, NN * sizeof(int), stream);
  k_count<<<2048, 256, 0, stream>>>(ei, counts);
  k_scan<<<1, 1024, 0, stream>>>(counts, rowptr, cursor);
  k_fill<<<2048, 256, 0, stream>>>(ei, cursor, eidx);

  // 1) p = x @ fW1
  k_gemm_first<<<(NN + 63) / 64, 256, 0, stream>>>(x, fW1, buf0);

  // 2) first conv: gather(p) -> agg; MLP -> buf2 (h0)
  k_gather<<<4096, 256, 0, stream>>>(buf0, rowptr, eidx, buf1);
  k_mlp_first<<<2048, 256, 0, stream>>>(buf0, buf1, eps + 0, fb1, fW2, fb2,
                                        bn_g, bn_b, bn_m, bn_v, buf2);

  // 3) layer 0: buf2 -> buf0
  k_gather<<<4096, 256, 0, stream>>>(buf2, rowptr, eidx, buf1);
  k_mlp_layer<<<2048, 256, 0, stream>>>(buf2, buf1, eps + 1, W1s, b1s, W2s,
                                        b2s, bn_g + HH, bn_b + HH, bn_m + HH,
                                        bn_v + HH, buf0);

  // 4) layer 1: buf0 -> buf2
  k_gather<<<4096, 256, 0, stream>>>(buf0, rowptr, eidx, buf1);
  k_mlp_layer<<<2048, 256, 0, stream>>>(buf0, buf1, eps + 2, W1s + HH * HH,
                                        b1s + HH, W2s + HH * HH, b2s + HH,
                                        bn_g + 2 * HH, bn_b + 2 * HH,
                                        bn_m + 2 * HH, bn_v + 2 * HH, buf2);

  // 5) readout -> out
  k_readout<<<1024, 256, 0, stream>>>(buf2, l1W, l1b, l2W, l2b, out);
}

// Round 4
// 631.383 us; speedup vs baseline: 1.1543x; 1.1543x over previous
//
#include <hip/hip_runtime.h>
#include <math.h>

#define NN 50000
#define EE 800000
#define FIN 100
#define HH 64
#define CC 18
#define NB 49  // scan blocks: ceil(NN/1024)

// ---------------- p = x @ fW1  (no bias; bias folded after aggregation) ----
__global__ __launch_bounds__(256) void k_gemm_first(
    const float* __restrict__ x, const float* __restrict__ W,
    float* __restrict__ p) {
  __shared__ float Ws[FIN * HH];   // 25.6 KB
  __shared__ float xs[64 * FIN];   // 25.6 KB
  int t = threadIdx.x;
  for (int i = t; i < FIN * HH; i += 256) Ws[i] = W[i];
  int n0 = blockIdx.x * 64;
  for (int i = t; i < 64 * FIN; i += 256) {
    int r = i / FIN, c = i - r * FIN;
    int n = n0 + r;
    xs[i] = (n < NN) ? x[n * FIN + c] : 0.f;
  }
  __syncthreads();
  int j = t & 63, nl = t >> 6;
  float acc[16];
#pragma unroll
  for (int q = 0; q < 16; ++q) acc[q] = 0.f;
  for (int k = 0; k < FIN; ++k) {
    float w = Ws[k * HH + j];
#pragma unroll
    for (int q = 0; q < 16; ++q)
      acc[q] = fmaf(xs[(nl + q * 4) * FIN + k], w, acc[q]);
  }
#pragma unroll
  for (int q = 0; q < 16; ++q) {
    int n = n0 + nl + q * 4;
    if (n < NN) p[n * HH + j] = acc[q];
  }
}

// ---------------- CSR build ------------------------------------------------
__global__ __launch_bounds__(256) void k_count(const int* __restrict__ ei,
                                               int* __restrict__ counts) {
  for (int e = blockIdx.x * 256 + threadIdx.x; e < EE; e += gridDim.x * 256)
    atomicAdd(&counts[ei[EE + e]], 1);
}

__device__ __forceinline__ void load4_guard(const int* __restrict__ a, int i4,
                                            int& c0, int& c1, int& c2,
                                            int& c3) {
  if (i4 + 3 < NN) {
    int4 v = *reinterpret_cast<const int4*>(a + i4);
    c0 = v.x; c1 = v.y; c2 = v.z; c3 = v.w;
  } else {
    c0 = (i4 < NN) ? a[i4] : 0;
    c1 = (i4 + 1 < NN) ? a[i4 + 1] : 0;
    c2 = (i4 + 2 < NN) ? a[i4 + 2] : 0;
    c3 = (i4 + 3 < NN) ? a[i4 + 3] : 0;
  }
}

// phase 1: per-block sums of 1024 counts
__global__ __launch_bounds__(256) void k_bsum(const int* __restrict__ counts,
                                              int* __restrict__ bsum) {
  __shared__ int ws[4];
  int t = threadIdx.x, lane = t & 63, wid = t >> 6;
  int i4 = blockIdx.x * 1024 + t * 4;
  int c0, c1, c2, c3;
  load4_guard(counts, i4, c0, c1, c2, c3);
  int s = c0 + c1 + c2 + c3;
#pragma unroll
  for (int m = 32; m >= 1; m >>= 1) s += __shfl_xor(s, m);
  if (lane == 0) ws[wid] = s;
  __syncthreads();
  if (t == 0) bsum[blockIdx.x] = ws[0] + ws[1] + ws[2] + ws[3];
}

// phase 2: single wave scans NB block sums -> exclusive offsets + total
__global__ __launch_bounds__(64) void k_bscan(const int* __restrict__ bsum,
                                              int* __restrict__ boff,
                                              int* __restrict__ rowptr) {
  int lane = threadIdx.x;
  int v = (lane < NB) ? bsum[lane] : 0;
  int x = v;
#pragma unroll
  for (int off = 1; off < 64; off <<= 1) {
    int y = __shfl_up(x, off);
    if (lane >= off) x += y;
  }
  if (lane < NB) boff[lane] = x - v;
  if (lane == NB - 1) rowptr[NN] = x;
}

// phase 3: per-block exclusive prefix -> rowptr & cursor
__global__ __launch_bounds__(256) void k_rowptr(const int* __restrict__ counts,
                                                const int* __restrict__ boff,
                                                int* __restrict__ rowptr,
                                                int* __restrict__ cursor) {
  __shared__ int wtot[4];
  int t = threadIdx.x, lane = t & 63, wid = t >> 6;
  int i4 = blockIdx.x * 1024 + t * 4;
  int c0, c1, c2, c3;
  load4_guard(counts, i4, c0, c1, c2, c3);
  int s = c0 + c1 + c2 + c3;
  int x = s;
#pragma unroll
  for (int off = 1; off < 64; off <<= 1) {
    int y = __shfl_up(x, off);
    if (lane >= off) x += y;
  }
  if (lane == 63) wtot[wid] = x;
  __syncthreads();
  int base = boff[blockIdx.x];
  for (int w = 0; w < wid; ++w) base += wtot[w];
  int p = base + x - s;  // exclusive prefix for this thread's 4 elems
  int p0 = p, p1 = p0 + c0, p2 = p1 + c1, p3 = p2 + c2;
  if (i4 + 3 < NN) {
    *reinterpret_cast<int4*>(rowptr + i4) = make_int4(p0, p1, p2, p3);
    *reinterpret_cast<int4*>(cursor + i4) = make_int4(p0, p1, p2, p3);
  } else {
    if (i4 < NN) { rowptr[i4] = p0; cursor[i4] = p0; }
    if (i4 + 1 < NN) { rowptr[i4 + 1] = p1; cursor[i4 + 1] = p1; }
    if (i4 + 2 < NN) { rowptr[i4 + 2] = p2; cursor[i4 + 2] = p2; }
    if (i4 + 3 < NN) { rowptr[i4 + 3] = p3; cursor[i4 + 3] = p3; }
  }
}

__global__ __launch_bounds__(256) void k_fill(const int* __restrict__ ei,
                                              int* __restrict__ cursor,
                                              int* __restrict__ eidx) {
  for (int e = blockIdx.x * 256 + threadIdx.x; e < EE; e += gridDim.x * 256) {
    int s = ei[e], d = ei[EE + e];
    int pos = atomicAdd(&cursor[d], 1);
    eidx[pos] = s;
  }
}

// ---------------- gather: agg[n][:] = sum feat[src][:] over in-edges -------
// float4 scheme: lane j covers edge sub-slot g=j>>4, col group c4=j&15.
__global__ __launch_bounds__(256) void k_gather(
    const float* __restrict__ feat, const int* __restrict__ rowptr,
    const int* __restrict__ eidx, float* __restrict__ agg) {
  int j = threadIdx.x & 63, wv = threadIdx.x >> 6;
  int g = j >> 4, c4 = j & 15;
  int wave = blockIdx.x * 4 + wv;
  int nw = gridDim.x * 4;
  for (int n = wave; n < NN; n += nw) {
    int beg = rowptr[n], end = rowptr[n + 1];
    float ax = 0.f, ay = 0.f, az = 0.f, aw = 0.f;
    for (int i0 = beg; i0 < end; i0 += 64) {
      int cnt = min(end - i0, 64);
      int eid = (j < cnt) ? eidx[i0 + j] : 0;
      for (int k = 0; k < cnt; k += 4) {
        int e = k + g;
        int se = __shfl(eid, e);
        if (e < cnt) {
          float4 v = *reinterpret_cast<const float4*>(feat + se * HH + c4 * 4);
          ax += v.x; ay += v.y; az += v.z; aw += v.w;
        }
      }
    }
    // combine edge sub-slots g: lanes j, j^16, j^32, j^48 hold same cols
    ax += __shfl_xor(ax, 16); ay += __shfl_xor(ay, 16);
    az += __shfl_xor(az, 16); aw += __shfl_xor(aw, 16);
    ax += __shfl_xor(ax, 32); ay += __shfl_xor(ay, 32);
    az += __shfl_xor(az, 32); aw += __shfl_xor(aw, 32);
    if (g == 0)
      *reinterpret_cast<float4*>(agg + n * HH + c4 * 4) =
          make_float4(ax, ay, az, aw);
  }
}

// -------- first conv MLP: z=(1+e)p+agg+b1; relu; @W2+b2; relu; BN ----------
__global__ __launch_bounds__(256) void k_mlp_first(
    const float* __restrict__ p, const float* __restrict__ agg,
    const float* __restrict__ epsv, const float* __restrict__ b1,
    const float* __restrict__ W2, const float* __restrict__ b2,
    const float* __restrict__ g, const float* __restrict__ be,
    const float* __restrict__ mu, const float* __restrict__ var,
    float* __restrict__ out) {
  __shared__ float W2s[HH * HH];  // 16 KB
  int t = threadIdx.x;
  for (int i = t; i < HH * HH; i += 256) W2s[i] = W2[i];
  __syncthreads();
  int j = t & 63, wv = t >> 6;
  float e0 = 1.f + epsv[0];
  float b1j = b1[j], b2j = b2[j];
  float sj = g[j] * rsqrtf(var[j] + 1e-5f);
  float bj = be[j] - mu[j] * sj;
  int wave = blockIdx.x * 4 + wv;
  int nw = gridDim.x * 4;
  for (int n = wave; n < NN; n += nw) {
    float a = fmaf(e0, p[n * HH + j], agg[n * HH + j]) + b1j;
    float tv = fmaxf(a, 0.f);
    float u = b2j;
#pragma unroll
    for (int k = 0; k < HH; ++k)
      u = fmaf(__shfl(tv, k), W2s[k * HH + j], u);
    float h = fmaxf(u, 0.f);
    out[n * HH + j] = fmaf(h, sj, bj);
  }
}

// -------- GIN layer MLP: z=(1+e)h+agg; relu(z@W1+b1)@W2+b2; relu; BN -------
__global__ __launch_bounds__(256) void k_mlp_layer(
    const float* __restrict__ h, const float* __restrict__ agg,
    const float* __restrict__ epsv, const float* __restrict__ W1,
    const float* __restrict__ b1, const float* __restrict__ W2,
    const float* __restrict__ b2, const float* __restrict__ g,
    const float* __restrict__ be, const float* __restrict__ mu,
    const float* __restrict__ var, float* __restrict__ out) {
  __shared__ float W1s[HH * HH];
  __shared__ float W2s[HH * HH];  // 32 KB total
  int t = threadIdx.x;
  for (int i = t; i < HH * HH; i += 256) {
    W1s[i] = W1[i];
    W2s[i] = W2[i];
  }
  __syncthreads();
  int j = t & 63, wv = t >> 6;
  float e0 = 1.f + epsv[0];
  float b1j = b1[j], b2j = b2[j];
  float sj = g[j] * rsqrtf(var[j] + 1e-5f);
  float bj = be[j] - mu[j] * sj;
  int wave = blockIdx.x * 4 + wv;
  int nw = gridDim.x * 4;
  for (int n = wave; n < NN; n += nw) {
    float z = fmaf(e0, h[n * HH + j], agg[n * HH + j]);
    float tv = b1j;
#pragma unroll
    for (int k = 0; k < HH; ++k)
      tv = fmaf(__shfl(z, k), W1s[k * HH + j], tv);
    tv = fmaxf(tv, 0.f);
    float u = b2j;
#pragma unroll
    for (int k = 0; k < HH; ++k)
      u = fmaf(__shfl(tv, k), W2s[k * HH + j], u);
    float hv = fmaxf(u, 0.f);
    out[n * HH + j] = fmaf(hv, sj, bj);
  }
}

// -------- readout: relu(h@L1+b)@L2+b2 -> log_softmax -----------------------
__global__ __launch_bounds__(256) void k_readout(
    const float* __restrict__ h, const float* __restrict__ W1,
    const float* __restrict__ b1, const float* __restrict__ W2,
    const float* __restrict__ b2, float* __restrict__ out) {
  __shared__ float W1s[HH * HH];
  __shared__ float W2s[HH * CC + 64];
  int t = threadIdx.x;
  for (int i = t; i < HH * HH; i += 256) W1s[i] = W1[i];
  for (int i = t; i < HH * CC + 64; i += 256)
    W2s[i] = (i < HH * CC) ? W2[i] : 0.f;
  __syncthreads();
  int j = t & 63, wv = t >> 6;
  float b1j = b1[j];
  float b2j = (j < CC) ? b2[j] : 0.f;
  int wave = blockIdx.x * 4 + wv;
  int nw = gridDim.x * 4;
  for (int n = wave; n < NN; n += nw) {
    float hv = h[n * HH + j];
    float r = b1j;
#pragma unroll
    for (int k = 0; k < HH; ++k)
      r = fmaf(__shfl(hv, k), W1s[k * HH + j], r);
    r = fmaxf(r, 0.f);
    float o = b2j;
#pragma unroll
    for (int k = 0; k < HH; ++k) {
      float rk = __shfl(r, k);
      o = fmaf(rk, W2s[k * CC + j], o);  // lanes >=18 compute garbage, masked
    }
    float om = (j < CC) ? o : -3.4e38f;
    float mx = om;
#pragma unroll
    for (int m = 32; m >= 1; m >>= 1) mx = fmaxf(mx, __shfl_xor(mx, m));
    float ex = (j < CC) ? expf(o - mx) : 0.f;
    float sm = ex;
#pragma unroll
    for (int m = 32; m >= 1; m >>= 1) sm += __shfl_xor(sm, m);
    if (j < CC) out[n * CC + j] = o - mx - logf(sm);
  }
}

extern "C" void kernel_launch(void* const* d_in, const int* in_sizes, int n_in,
                              void* d_out, int out_size, void* d_ws,
                              size_t ws_size, hipStream_t stream) {
  const float* x = (const float*)d_in[0];
  const int* ei = (const int*)d_in[1];
  const float* eps = (const float*)d_in[2];
  const float* fW1 = (const float*)d_in[3];
  const float* fb1 = (const float*)d_in[4];
  const float* fW2 = (const float*)d_in[5];
  const float* fb2 = (const float*)d_in[6];
  const float* W1s = (const float*)d_in[7];
  const float* b1s = (const float*)d_in[8];
  const float* W2s = (const float*)d_in[9];
  const float* b2s = (const float*)d_in[10];
  const float* bn_g = (const float*)d_in[11];
  const float* bn_b = (const float*)d_in[12];
  const float* bn_m = (const float*)d_in[13];
  const float* bn_v = (const float*)d_in[14];
  const float* l1W = (const float*)d_in[15];
  const float* l1b = (const float*)d_in[16];
  const float* l2W = (const float*)d_in[17];
  const float* l2b = (const float*)d_in[18];
  float* out = (float*)d_out;

  // ws layout: eidx[EE] | rowptr[NN+1] | boff[NB] | bsum[NB] | pad |
  //            buf0 | buf1(agg) | buf2
  // counts/cursor overlay buf0 (dead before k_gemm_first writes buf0).
  int* eidx = (int*)d_ws;
  int* rowptr = eidx + EE;
  int* boff = rowptr + NN + 1;
  int* bsum = boff + NB;
  size_t int_elems = (size_t)EE + NN + 1 + 2 * NB;
  size_t f_off = (int_elems + 3) & ~(size_t)3;  // 16B align
  const size_t NH = (size_t)NN * HH;
  float* buf0 = (float*)d_ws + f_off;  // p / h
  float* buf1 = buf0 + NH;             // agg
  float* buf2 = buf1 + NH;             // h alt
  int* counts = (int*)buf0;            // overlay, dead after k_rowptr
  int* cursor = counts + NN;           // overlay, dead after k_fill

  // CSR build
  hipMemsetAsync(counts, 0, NN * sizeof(int), stream);
  k_count<<<2048, 256, 0, stream>>>(ei, counts);
  k_bsum<<<NB, 256, 0, stream>>>(counts, bsum);
  k_bscan<<<1, 64, 0, stream>>>(bsum, boff, rowptr);
  k_rowptr<<<NB, 256, 0, stream>>>(counts, boff, rowptr, cursor);
  k_fill<<<2048, 256, 0, stream>>>(ei, cursor, eidx);

  // 1) p = x @ fW1
  k_gemm_first<<<(NN + 63) / 64, 256, 0, stream>>>(x, fW1, buf0);

  // 2) first conv: gather(p) -> agg; MLP -> buf2 (h0)
  k_gather<<<4096, 256, 0, stream>>>(buf0, rowptr, eidx, buf1);
  k_mlp_first<<<2048, 256, 0, stream>>>(buf0, buf1, eps + 0, fb1, fW2, fb2,
                                        bn_g, bn_b, bn_m, bn_v, buf2);

  // 3) layer 0: buf2 -> buf0
  k_gather<<<4096, 256, 0, stream>>>(buf2, rowptr, eidx, buf1);
  k_mlp_layer<<<2048, 256, 0, stream>>>(buf2, buf1, eps + 1, W1s, b1s, W2s,
                                        b2s, bn_g + HH, bn_b + HH, bn_m + HH,
                                        bn_v + HH, buf0);

  // 4) layer 1: buf0 -> buf2
  k_gather<<<4096, 256, 0, stream>>>(buf0, rowptr, eidx, buf1);
  k_mlp_layer<<<2048, 256, 0, stream>>>(buf0, buf1, eps + 2, W1s + HH * HH,
                                        b1s + HH, W2s + HH * HH, b2s + HH,
                                        bn_g + 2 * HH, bn_b + 2 * HH,
                                        bn_m + 2 * HH, bn_v + 2 * HH, buf2);

  // 5) readout -> out
  k_readout<<<1024, 256, 0, stream>>>(buf2, l1W, l1b, l2W, l2b, out);
}

// Round 5
// 477.529 us; speedup vs baseline: 1.5262x; 1.3222x over previous
//
#include <hip/hip_runtime.h>
#include <math.h>

#define NN 50000
#define EE 800000
#define FIN 100
#define HH 64
#define CC 18
#define NB 49  // scan blocks: ceil(NN/1024)

// ---------------- p = x @ fW1  (no bias; bias folded after aggregation) ----
__global__ __launch_bounds__(256) void k_gemm_first(
    const float* __restrict__ x, const float* __restrict__ W,
    float* __restrict__ p) {
  __shared__ float Ws[FIN * HH];   // 25.6 KB
  __shared__ float xs[64 * FIN];   // 25.6 KB
  int t = threadIdx.x;
  for (int i = t; i < FIN * HH; i += 256) Ws[i] = W[i];
  int n0 = blockIdx.x * 64;
  for (int i = t; i < 64 * FIN; i += 256) {
    int r = i / FIN, c = i - r * FIN;
    int n = n0 + r;
    xs[i] = (n < NN) ? x[n * FIN + c] : 0.f;
  }
  __syncthreads();
  int j = t & 63, nl = t >> 6;
  float acc[16];
#pragma unroll
  for (int q = 0; q < 16; ++q) acc[q] = 0.f;
  for (int k = 0; k < FIN; ++k) {
    float w = Ws[k * HH + j];
#pragma unroll
    for (int q = 0; q < 16; ++q)
      acc[q] = fmaf(xs[(nl + q * 4) * FIN + k], w, acc[q]);
  }
#pragma unroll
  for (int q = 0; q < 16; ++q) {
    int n = n0 + nl + q * 4;
    if (n < NN) p[n * HH + j] = acc[q];
  }
}

// ---------------- CSR build ------------------------------------------------
__global__ __launch_bounds__(256) void k_count(const int* __restrict__ ei,
                                               int* __restrict__ counts) {
  for (int e = blockIdx.x * 256 + threadIdx.x; e < EE; e += gridDim.x * 256)
    atomicAdd(&counts[ei[EE + e]], 1);
}

__device__ __forceinline__ void load4_guard(const int* __restrict__ a, int i4,
                                            int& c0, int& c1, int& c2,
                                            int& c3) {
  if (i4 + 3 < NN) {
    int4 v = *reinterpret_cast<const int4*>(a + i4);
    c0 = v.x; c1 = v.y; c2 = v.z; c3 = v.w;
  } else {
    c0 = (i4 < NN) ? a[i4] : 0;
    c1 = (i4 + 1 < NN) ? a[i4 + 1] : 0;
    c2 = (i4 + 2 < NN) ? a[i4 + 2] : 0;
    c3 = (i4 + 3 < NN) ? a[i4 + 3] : 0;
  }
}

// phase 1: per-block sums of 1024 counts
__global__ __launch_bounds__(256) void k_bsum(const int* __restrict__ counts,
                                              int* __restrict__ bsum) {
  __shared__ int ws[4];
  int t = threadIdx.x, lane = t & 63, wid = t >> 6;
  int i4 = blockIdx.x * 1024 + t * 4;
  int c0, c1, c2, c3;
  load4_guard(counts, i4, c0, c1, c2, c3);
  int s = c0 + c1 + c2 + c3;
#pragma unroll
  for (int m = 32; m >= 1; m >>= 1) s += __shfl_xor(s, m);
  if (lane == 0) ws[wid] = s;
  __syncthreads();
  if (t == 0) bsum[blockIdx.x] = ws[0] + ws[1] + ws[2] + ws[3];
}

// phase 2: single wave scans NB block sums -> exclusive offsets + total
__global__ __launch_bounds__(64) void k_bscan(const int* __restrict__ bsum,
                                              int* __restrict__ boff,
                                              int* __restrict__ rowptr) {
  int lane = threadIdx.x;
  int v = (lane < NB) ? bsum[lane] : 0;
  int x = v;
#pragma unroll
  for (int off = 1; off < 64; off <<= 1) {
    int y = __shfl_up(x, off);
    if (lane >= off) x += y;
  }
  if (lane < NB) boff[lane] = x - v;
  if (lane == NB - 1) rowptr[NN] = x;
}

// phase 3: per-block exclusive prefix -> rowptr & cursor
__global__ __launch_bounds__(256) void k_rowptr(const int* __restrict__ counts,
                                                const int* __restrict__ boff,
                                                int* __restrict__ rowptr,
                                                int* __restrict__ cursor) {
  __shared__ int wtot[4];
  int t = threadIdx.x, lane = t & 63, wid = t >> 6;
  int i4 = blockIdx.x * 1024 + t * 4;
  int c0, c1, c2, c3;
  load4_guard(counts, i4, c0, c1, c2, c3);
  int s = c0 + c1 + c2 + c3;
  int x = s;
#pragma unroll
  for (int off = 1; off < 64; off <<= 1) {
    int y = __shfl_up(x, off);
    if (lane >= off) x += y;
  }
  if (lane == 63) wtot[wid] = x;
  __syncthreads();
  int base = boff[blockIdx.x];
  for (int w = 0; w < wid; ++w) base += wtot[w];
  int p = base + x - s;  // exclusive prefix for this thread's 4 elems
  int p0 = p, p1 = p0 + c0, p2 = p1 + c1, p3 = p2 + c2;
  if (i4 + 3 < NN) {
    *reinterpret_cast<int4*>(rowptr + i4) = make_int4(p0, p1, p2, p3);
    *reinterpret_cast<int4*>(cursor + i4) = make_int4(p0, p1, p2, p3);
  } else {
    if (i4 < NN) { rowptr[i4] = p0; cursor[i4] = p0; }
    if (i4 + 1 < NN) { rowptr[i4 + 1] = p1; cursor[i4 + 1] = p1; }
    if (i4 + 2 < NN) { rowptr[i4 + 2] = p2; cursor[i4 + 2] = p2; }
    if (i4 + 3 < NN) { rowptr[i4 + 3] = p3; cursor[i4 + 3] = p3; }
  }
}

__global__ __launch_bounds__(256) void k_fill(const int* __restrict__ ei,
                                              int* __restrict__ cursor,
                                              int* __restrict__ eidx) {
  for (int e = blockIdx.x * 256 + threadIdx.x; e < EE; e += gridDim.x * 256) {
    int s = ei[e], d = ei[EE + e];
    int pos = atomicAdd(&cursor[d], 1);
    eidx[pos] = s;
  }
}

// ---------------- gather: agg[n][:] = sum feat[src][:] over in-edges -------
__global__ __launch_bounds__(256) void k_gather(
    const float* __restrict__ feat, const int* __restrict__ rowptr,
    const int* __restrict__ eidx, float* __restrict__ agg) {
  int j = threadIdx.x & 63, wv = threadIdx.x >> 6;
  int g = j >> 4, c4 = j & 15;
  int wave = blockIdx.x * 4 + wv;
  int nw = gridDim.x * 4;
  for (int n = wave; n < NN; n += nw) {
    int beg = rowptr[n], end = rowptr[n + 1];
    float ax = 0.f, ay = 0.f, az = 0.f, aw = 0.f;
    for (int i0 = beg; i0 < end; i0 += 64) {
      int cnt = min(end - i0, 64);
      int eid = (j < cnt) ? eidx[i0 + j] : 0;
      for (int k = 0; k < cnt; k += 4) {
        int e = k + g;
        int se = __shfl(eid, e);
        if (e < cnt) {
          float4 v = *reinterpret_cast<const float4*>(feat + se * HH + c4 * 4);
          ax += v.x; ay += v.y; az += v.z; aw += v.w;
        }
      }
    }
    ax += __shfl_xor(ax, 16); ay += __shfl_xor(ay, 16);
    az += __shfl_xor(az, 16); aw += __shfl_xor(aw, 16);
    ax += __shfl_xor(ax, 32); ay += __shfl_xor(ay, 32);
    az += __shfl_xor(az, 32); aw += __shfl_xor(aw, 32);
    if (g == 0)
      *reinterpret_cast<float4*>(agg + n * HH + c4 * 4) =
          make_float4(ax, ay, az, aw);
  }
}

// ---- tile GEMM helper: acc[q] (16 rows x col j) += Zs(rows) @ Ws(col j) ---
__device__ __forceinline__ void tile_gemm(const float* __restrict__ Zs,
                                          const float* __restrict__ Ws,
                                          int nl, int j, float* acc) {
  const float4* Zv = reinterpret_cast<const float4*>(Zs);
  for (int k4 = 0; k4 < 16; ++k4) {
    float w0 = Ws[(k4 * 4 + 0) * HH + j];
    float w1 = Ws[(k4 * 4 + 1) * HH + j];
    float w2 = Ws[(k4 * 4 + 2) * HH + j];
    float w3 = Ws[(k4 * 4 + 3) * HH + j];
#pragma unroll
    for (int q = 0; q < 16; ++q) {
      float4 z = Zv[(nl + q * 4) * 16 + k4];
      acc[q] = fmaf(z.x, w0, acc[q]);
      acc[q] = fmaf(z.y, w1, acc[q]);
      acc[q] = fmaf(z.z, w2, acc[q]);
      acc[q] = fmaf(z.w, w3, acc[q]);
    }
  }
}

// -------- first conv MLP tile: T=relu((1+e)p+agg+b1); out=BN(relu(T@W2+b2))
__global__ __launch_bounds__(256) void k_mlp_first(
    const float* __restrict__ p, const float* __restrict__ agg,
    const float* __restrict__ epsv, const float* __restrict__ b1,
    const float* __restrict__ W2, const float* __restrict__ b2,
    const float* __restrict__ g, const float* __restrict__ be,
    const float* __restrict__ mu, const float* __restrict__ var,
    float* __restrict__ out) {
  __shared__ float Zs[HH * HH];   // 16 KB
  __shared__ float W2s[HH * HH];  // 16 KB
  int t = threadIdx.x;
  int n0 = blockIdx.x * 64;
  float e0 = 1.f + epsv[0];
  for (int i4 = t * 4; i4 < HH * HH; i4 += 1024)
    *reinterpret_cast<float4*>(W2s + i4) =
        *reinterpret_cast<const float4*>(W2 + i4);
  for (int i4 = t * 4; i4 < HH * HH; i4 += 1024) {
    int gw = n0 * HH + i4;
    float4 z4 = make_float4(0.f, 0.f, 0.f, 0.f);
    if (gw < NN * HH) {
      float4 pv = *reinterpret_cast<const float4*>(p + gw);
      float4 av = *reinterpret_cast<const float4*>(agg + gw);
      float4 bv = *reinterpret_cast<const float4*>(b1 + (i4 & 63));
      z4.x = fmaxf(fmaf(e0, pv.x, av.x) + bv.x, 0.f);
      z4.y = fmaxf(fmaf(e0, pv.y, av.y) + bv.y, 0.f);
      z4.z = fmaxf(fmaf(e0, pv.z, av.z) + bv.z, 0.f);
      z4.w = fmaxf(fmaf(e0, pv.w, av.w) + bv.w, 0.f);
    }
    *reinterpret_cast<float4*>(Zs + i4) = z4;
  }
  __syncthreads();
  int j = t & 63, nl = t >> 6;
  float b2j = b2[j];
  float sj = g[j] * rsqrtf(var[j] + 1e-5f);
  float bj = be[j] - mu[j] * sj;
  float acc[16];
#pragma unroll
  for (int q = 0; q < 16; ++q) acc[q] = b2j;
  tile_gemm(Zs, W2s, nl, j, acc);
#pragma unroll
  for (int q = 0; q < 16; ++q) {
    int n = n0 + nl + q * 4;
    if (n < NN) out[n * HH + j] = fmaf(fmaxf(acc[q], 0.f), sj, bj);
  }
}

// -------- GIN layer MLP tile: Z=(1+e)h+agg; T=relu(Z@W1+b1);
//          out = BN(relu(T@W2+b2))
__global__ __launch_bounds__(256) void k_mlp_layer(
    const float* __restrict__ h, const float* __restrict__ agg,
    const float* __restrict__ epsv, const float* __restrict__ W1,
    const float* __restrict__ b1, const float* __restrict__ W2,
    const float* __restrict__ b2, const float* __restrict__ g,
    const float* __restrict__ be, const float* __restrict__ mu,
    const float* __restrict__ var, float* __restrict__ out) {
  __shared__ float Zs[HH * HH];
  __shared__ float W1s[HH * HH];
  __shared__ float W2s[HH * HH];  // 48 KB total
  int t = threadIdx.x;
  int n0 = blockIdx.x * 64;
  float e0 = 1.f + epsv[0];
  for (int i4 = t * 4; i4 < HH * HH; i4 += 1024) {
    *reinterpret_cast<float4*>(W1s + i4) =
        *reinterpret_cast<const float4*>(W1 + i4);
    *reinterpret_cast<float4*>(W2s + i4) =
        *reinterpret_cast<const float4*>(W2 + i4);
  }
  for (int i4 = t * 4; i4 < HH * HH; i4 += 1024) {
    int gw = n0 * HH + i4;
    float4 z4 = make_float4(0.f, 0.f, 0.f, 0.f);
    if (gw < NN * HH) {
      float4 hv = *reinterpret_cast<const float4*>(h + gw);
      float4 av = *reinterpret_cast<const float4*>(agg + gw);
      z4.x = fmaf(e0, hv.x, av.x);
      z4.y = fmaf(e0, hv.y, av.y);
      z4.z = fmaf(e0, hv.z, av.z);
      z4.w = fmaf(e0, hv.w, av.w);
    }
    *reinterpret_cast<float4*>(Zs + i4) = z4;
  }
  __syncthreads();
  int j = t & 63, nl = t >> 6;
  float b1j = b1[j], b2j = b2[j];
  float sj = g[j] * rsqrtf(var[j] + 1e-5f);
  float bj = be[j] - mu[j] * sj;
  float acc[16];
#pragma unroll
  for (int q = 0; q < 16; ++q) acc[q] = b1j;
  tile_gemm(Zs, W1s, nl, j, acc);
  // write T back into own wave's rows (intra-wave dependency only: no barrier)
#pragma unroll
  for (int q = 0; q < 16; ++q) Zs[(nl + q * 4) * HH + j] = fmaxf(acc[q], 0.f);
#pragma unroll
  for (int q = 0; q < 16; ++q) acc[q] = b2j;
  tile_gemm(Zs, W2s, nl, j, acc);
#pragma unroll
  for (int q = 0; q < 16; ++q) {
    int n = n0 + nl + q * 4;
    if (n < NN) out[n * HH + j] = fmaf(fmaxf(acc[q], 0.f), sj, bj);
  }
}

// -------- readout tile: T=relu(h@L1+b1); o=T@L2+b2 -> log_softmax ----------
__global__ __launch_bounds__(256) void k_readout(
    const float* __restrict__ h, const float* __restrict__ W1,
    const float* __restrict__ b1, const float* __restrict__ W2,
    const float* __restrict__ b2, float* __restrict__ out) {
  __shared__ float Zs[HH * HH];
  __shared__ float W1s[HH * HH];
  __shared__ float W2s[HH * CC + 64];  // pad: idle lanes read in-bounds junk
  int t = threadIdx.x;
  int n0 = blockIdx.x * 64;
  for (int i4 = t * 4; i4 < HH * HH; i4 += 1024)
    *reinterpret_cast<float4*>(W1s + i4) =
        *reinterpret_cast<const float4*>(W1 + i4);
  for (int i = t; i < HH * CC + 64; i += 256)
    W2s[i] = (i < HH * CC) ? W2[i] : 0.f;
  for (int i4 = t * 4; i4 < HH * HH; i4 += 1024) {
    int gw = n0 * HH + i4;
    float4 z4 = make_float4(0.f, 0.f, 0.f, 0.f);
    if (gw < NN * HH) z4 = *reinterpret_cast<const float4*>(h + gw);
    *reinterpret_cast<float4*>(Zs + i4) = z4;
  }
  __syncthreads();
  int j = t & 63, nl = t >> 6;
  float b1j = b1[j];
  float b2j = (j < CC) ? b2[j] : 0.f;
  float acc[16];
#pragma unroll
  for (int q = 0; q < 16; ++q) acc[q] = b1j;
  tile_gemm(Zs, W1s, nl, j, acc);
#pragma unroll
  for (int q = 0; q < 16; ++q) Zs[(nl + q * 4) * HH + j] = fmaxf(acc[q], 0.f);
  // stage 2: o = T @ W2 (+b2), cols j<CC valid
#pragma unroll
  for (int q = 0; q < 16; ++q) acc[q] = b2j;
  {
    const float4* Zv = reinterpret_cast<const float4*>(Zs);
    for (int k4 = 0; k4 < 16; ++k4) {
      float w0 = W2s[(k4 * 4 + 0) * CC + j];
      float w1 = W2s[(k4 * 4 + 1) * CC + j];
      float w2 = W2s[(k4 * 4 + 2) * CC + j];
      float w3 = W2s[(k4 * 4 + 3) * CC + j];
#pragma unroll
      for (int q = 0; q < 16; ++q) {
        float4 z = Zv[(nl + q * 4) * 16 + k4];
        acc[q] = fmaf(z.x, w0, acc[q]);
        acc[q] = fmaf(z.y, w1, acc[q]);
        acc[q] = fmaf(z.z, w2, acc[q]);
        acc[q] = fmaf(z.w, w3, acc[q]);
      }
    }
  }
#pragma unroll
  for (int q = 0; q < 16; ++q) {
    float o = acc[q];
    float om = (j < CC) ? o : -3.4e38f;
    float mx = om;
#pragma unroll
    for (int m = 32; m >= 1; m >>= 1) mx = fmaxf(mx, __shfl_xor(mx, m));
    float ex = (j < CC) ? expf(o - mx) : 0.f;
    float sm = ex;
#pragma unroll
    for (int m = 32; m >= 1; m >>= 1) sm += __shfl_xor(sm, m);
    int n = n0 + nl + q * 4;
    if (n < NN && j < CC) out[n * CC + j] = o - mx - logf(sm);
  }
}

extern "C" void kernel_launch(void* const* d_in, const int* in_sizes, int n_in,
                              void* d_out, int out_size, void* d_ws,
                              size_t ws_size, hipStream_t stream) {
  const float* x = (const float*)d_in[0];
  const int* ei = (const int*)d_in[1];
  const float* eps = (const float*)d_in[2];
  const float* fW1 = (const float*)d_in[3];
  const float* fb1 = (const float*)d_in[4];
  const float* fW2 = (const float*)d_in[5];
  const float* fb2 = (const float*)d_in[6];
  const float* W1s = (const float*)d_in[7];
  const float* b1s = (const float*)d_in[8];
  const float* W2s = (const float*)d_in[9];
  const float* b2s = (const float*)d_in[10];
  const float* bn_g = (const float*)d_in[11];
  const float* bn_b = (const float*)d_in[12];
  const float* bn_m = (const float*)d_in[13];
  const float* bn_v = (const float*)d_in[14];
  const float* l1W = (const float*)d_in[15];
  const float* l1b = (const float*)d_in[16];
  const float* l2W = (const float*)d_in[17];
  const float* l2b = (const float*)d_in[18];
  float* out = (float*)d_out;

  // ws layout: eidx[EE] | rowptr[NN+1] | boff[NB] | bsum[NB] | pad |
  //            buf0 | buf1(agg) | buf2
  int* eidx = (int*)d_ws;
  int* rowptr = eidx + EE;
  int* boff = rowptr + NN + 1;
  int* bsum = boff + NB;
  size_t int_elems = (size_t)EE + NN + 1 + 2 * NB;
  size_t f_off = (int_elems + 3) & ~(size_t)3;  // 16B align
  const size_t NH = (size_t)NN * HH;
  float* buf0 = (float*)d_ws + f_off;  // p / h
  float* buf1 = buf0 + NH;             // agg
  float* buf2 = buf1 + NH;             // h alt
  int* counts = (int*)buf0;            // overlay, dead after k_rowptr
  int* cursor = counts + NN;           // overlay, dead after k_fill

  const int TB = (NN + 63) / 64;  // 782 tile blocks

  // CSR build
  hipMemsetAsync(counts, 0, NN * sizeof(int), stream);
  k_count<<<2048, 256, 0, stream>>>(ei, counts);
  k_bsum<<<NB, 256, 0, stream>>>(counts, bsum);
  k_bscan<<<1, 64, 0, stream>>>(bsum, boff, rowptr);
  k_rowptr<<<NB, 256, 0, stream>>>(counts, boff, rowptr, cursor);
  k_fill<<<2048, 256, 0, stream>>>(ei, cursor, eidx);

  // 1) p = x @ fW1
  k_gemm_first<<<TB, 256, 0, stream>>>(x, fW1, buf0);

  // 2) first conv: gather(p) -> agg; MLP tile -> buf2 (h0)
  k_gather<<<4096, 256, 0, stream>>>(buf0, rowptr, eidx, buf1);
  k_mlp_first<<<TB, 256, 0, stream>>>(buf0, buf1, eps + 0, fb1, fW2, fb2,
                                      bn_g, bn_b, bn_m, bn_v, buf2);

  // 3) layer 0: buf2 -> buf0
  k_gather<<<4096, 256, 0, stream>>>(buf2, rowptr, eidx, buf1);
  k_mlp_layer<<<TB, 256, 0, stream>>>(buf2, buf1, eps + 1, W1s, b1s, W2s,
                                      b2s, bn_g + HH, bn_b + HH, bn_m + HH,
                                      bn_v + HH, buf0);

  // 4) layer 1: buf0 -> buf2
  k_mlp_layer_wait:;
  k_gather<<<4096, 256, 0, stream>>>(buf0, rowptr, eidx, buf1);
  k_mlp_layer<<<TB, 256, 0, stream>>>(buf0, buf1, eps + 2, W1s + HH * HH,
                                      b1s + HH, W2s + HH * HH, b2s + HH,
                                      bn_g + 2 * HH, bn_b + 2 * HH,
                                      bn_m + 2 * HH, bn_v + 2 * HH, buf2);

  // 5) readout -> out
  k_readout<<<TB, 256, 0, stream>>>(buf2, l1W, l1b, l2W, l2b, out);
}